// Round 6
// baseline (1763.344 us; speedup 1.0000x reference)
//
#include <hip/hip_runtime.h>
#include <cstddef>

#define BB   8
#define VV   25
#define TT   128
#define CC   256
#define NHH  8
#define DKK  32
#define DFFF 1024
#define ITER 4
#define NN   (BB*VV)     // 200
#define NT   (NN*TT)     // 25600
#define LL1  (TT+1)      // 129
#define EPS_LN 1e-6f
#define EPS_BN 1e-5f
#define SLOPE  0.01f
#define SCALE_F 0.17677669529663687f   // 1/sqrt(32)

typedef unsigned short ushort_t;
typedef __attribute__((ext_vector_type(8))) short short8;
typedef __attribute__((ext_vector_type(4))) short short4_t;
typedef __attribute__((ext_vector_type(4))) float floatx4;

union U8 { short8 v; ushort_t u[8]; };

__device__ __forceinline__ float bf2f(ushort_t u) {
    union { unsigned int i; float f; } x; x.i = ((unsigned int)u) << 16; return x.f;
}
__device__ __forceinline__ ushort_t f2bf(float f) {
    union { float f; unsigned int i; } x; x.f = f;
    unsigned int r = x.i + 0x7FFFu + ((x.i >> 16) & 1u);   // RNE
    return (ushort_t)(r >> 16);
}

// load 32 bf16 (contiguous) -> f32 regs
__device__ __forceinline__ void ld32(const ushort_t* p, float* q) {
    #pragma unroll
    for (int c8 = 0; c8 < 4; c8++) {
        U8 u; u.v = *(const short8*)(p + c8*8);
        #pragma unroll
        for (int j = 0; j < 8; j++) q[c8*8+j] = bf2f(u.u[j]);
    }
}
__device__ __forceinline__ float dot32(const ushort_t* p, const float* q) {
    float s = 0.f;
    #pragma unroll
    for (int c8 = 0; c8 < 4; c8++) {
        U8 u; u.v = *(const short8*)(p + c8*8);
        #pragma unroll
        for (int j = 0; j < 8; j++) s += q[c8*8+j]*bf2f(u.u[j]);
    }
    return s;
}
__device__ __forceinline__ void acc32(const ushort_t* p, float e, float* av) {
    #pragma unroll
    for (int c8 = 0; c8 < 4; c8++) {
        U8 u; u.v = *(const short8*)(p + c8*8);
        #pragma unroll
        for (int j = 0; j < 8; j++) av[c8*8+j] += e*bf2f(u.u[j]);
    }
}

// ---------------------------------------------------------------------------
// strided cast/copy: dst[(i/per)*dstride + i%per] = src[i]
__global__ __launch_bounds__(256) void k_cast2(const float* __restrict__ src,
    ushort_t* __restrict__ dst, int per, int dstride, int total)
{
    int i = blockIdx.x*256 + threadIdx.x;
    if (i < total) dst[(size_t)(i/per)*dstride + (i%per)] = f2bf(src[i]);
}
__global__ __launch_bounds__(256) void k_copy2(const float* __restrict__ src,
    float* __restrict__ dst, int per, int dstride, int total)
{
    int i = blockIdx.x*256 + threadIdx.x;
    if (i < total) dst[(size_t)(i/per)*dstride + (i%per)] = src[i];
}

// ---------------------------------------------------------------------------
// embed: nodesf[nt][c] f32 TM + embs_bf TM + relay[n][c]=mean_t. LDS transpose.
__global__ __launch_bounds__(128) void k_embed(const float* __restrict__ data,
    float* __restrict__ nodesf, ushort_t* __restrict__ embs_bf, float* __restrict__ relay)
{
    __shared__ float tile[32][TT+1];
    int cc0 = blockIdx.x*32, n = blockIdx.y;
    int b = n / VV, v = n % VV, t = threadIdx.x;
    for (int cl = 0; cl < 32; cl++)
        tile[cl][t] = data[(((size_t)b*CC + cc0 + cl)*VV + v)*TT + t];
    __syncthreads();
    if (t < 32) {
        float s = 0.f;
        for (int tt = 0; tt < TT; tt++) s += tile[t][tt];
        relay[n*CC + cc0 + t] = s * (1.0f/TT);
    }
    #pragma unroll 8
    for (int it = 0; it < 32; it++) {
        int t_l = it*4 + (t >> 5), c_l = t & 31;
        float val = tile[c_l][t_l];
        size_t o = (size_t)(n*TT + t_l)*CC + cc0 + c_l;
        nodesf[o] = val;
        embs_bf[o] = f2bf(val);
    }
}

// ---------------------------------------------------------------------------
// LayerNorm TM in-place + bf16 TM copy. One wave per token.
__global__ __launch_bounds__(256) void k_layernorm(float* __restrict__ x,
    ushort_t* __restrict__ outb, const float* __restrict__ g, const float* __restrict__ b)
{
    int wave = threadIdx.x >> 6, lane = threadIdx.x & 63;
    size_t base = (size_t)(blockIdx.x*4 + wave)*CC + lane*4;
    float4 v = *(float4*)&x[base];
    float s  = v.x + v.y + v.z + v.w;
    float ss = v.x*v.x + v.y*v.y + v.z*v.z + v.w*v.w;
    #pragma unroll
    for (int o = 32; o; o >>= 1) { s += __shfl_xor(s, o); ss += __shfl_xor(ss, o); }
    float m = s * (1.0f/CC);
    float var = ss * (1.0f/CC) - m*m; if (var < 0.f) var = 0.f;
    float rs = rsqrtf(var + EPS_LN);
    float4 gg = *(const float4*)&g[lane*4];
    float4 bb = *(const float4*)&b[lane*4];
    v.x = (v.x - m)*rs*gg.x + bb.x;
    v.y = (v.y - m)*rs*gg.y + bb.y;
    v.z = (v.z - m)*rs*gg.z + bb.z;
    v.w = (v.w - m)*rs*gg.w + bb.w;
    *(float4*)&x[base] = v;
    ushort_t o4[4] = {f2bf(v.x), f2bf(v.y), f2bf(v.z), f2bf(v.w)};
    *(short4_t*)&outb[base] = *(short4_t*)o4;
}

// ---------------------------------------------------------------------------
// bf16 MFMA GEMM, token-major, m97-style K-loop:
//  - global_load_lds width=16 direct-to-LDS staging (no VGPR round trip)
//  - double-buffered LDS, ONE barrier per K-iter (loads for k+1 in flight
//    across the whole compute of k)
//  - LDS chunk layout [k-chunk][row]*16B: reads 2-way aliased = free
//  - XCD swizzle: pid&7 = xcd owns 25 m-tiles x all n-tiles (A fetched once)
// D[m=token][n=outch] = act(A[m,:]·B[n,:] + bias[n] (+BN(res)))
#define FL_RELU  1
#define FL_BF16  2
#define FL_RESBN 4
#define GLOBAL_ASP const __attribute__((address_space(1))) void*
#define LDS_ASP __attribute__((address_space(3))) void*
__global__ __launch_bounds__(256) void k_gemm_mfma(
    const ushort_t* __restrict__ A, const ushort_t* __restrict__ B,
    const float* __restrict__ bias,
    const float* rx, const float* __restrict__ ms,
    const float* __restrict__ bng, const float* __restrict__ bnb,
    float* outf, ushort_t* __restrict__ outb,
    int K, int ostride, int ntiles_n, int flags)
{
    // [buf][A:4096 | B:4096] ushorts; chunk t (=ch*128+row) at offset t*8
    __shared__ ushort_t lds[16384];   // 32 KB
    const int pid = blockIdx.x;
    const int xcd = pid & 7;
    const int idx = pid >> 3;
    const int n0 = (idx % ntiles_n) * 128;
    const int m0 = (xcd*25 + idx/ntiles_n) * 128;   // 200 m-tiles = 8 XCD x 25
    const int tid = threadIdx.x;
    const int lane = tid & 63, wave = tid >> 6;
    const int wbase = wave*64;                       // wave-uniform
    const int wm = (wave & 1) * 64, wn = (wave >> 1) * 64;
    const int fr = lane >> 4, fc = lane & 15;

    floatx4 acc[4][4];
    #pragma unroll
    for (int i = 0; i < 4; i++)
        #pragma unroll
        for (int j = 0; j < 4; j++) acc[i][j] = (floatx4){0.f,0.f,0.f,0.f};

    auto stage = [&](int kc, int b) {
        ushort_t* baseA = &lds[b*8192];
        ushort_t* baseB = &lds[b*8192 + 4096];
        #pragma unroll
        for (int it = 0; it < 2; it++) {
            int t0 = it*256 + wbase;            // uniform per wave
            int t = t0 + lane;
            int ch = t >> 7, row = t & 127;     // chunk index = ch*128+row
            const ushort_t* ga = A + (size_t)(m0 + row)*K + kc + ch*8;
            __builtin_amdgcn_global_load_lds((GLOBAL_ASP)ga,
                (LDS_ASP)(baseA + t0*8), 16, 0, 0);
            const ushort_t* gb = B + (size_t)(n0 + row)*K + kc + ch*8;
            __builtin_amdgcn_global_load_lds((GLOBAL_ASP)gb,
                (LDS_ASP)(baseB + t0*8), 16, 0, 0);
        }
    };

    const int KT = K >> 5;
    stage(0, 0);
    for (int kt = 0; kt < KT; kt++) {
        __syncthreads();    // drains vmcnt -> tile kt resident; syncs WAR on buf
        if (kt + 1 < KT) stage((kt+1) << 5, (kt+1) & 1);
        const ushort_t* baseA = &lds[(kt & 1)*8192];
        const ushort_t* baseB = &lds[(kt & 1)*8192 + 4096];
        short8 af[4], bfr[4];
        #pragma unroll
        for (int mi = 0; mi < 4; mi++)
            af[mi] = *(const short8*)&baseA[(fr*128 + wm + mi*16 + fc)*8];
        #pragma unroll
        for (int ni = 0; ni < 4; ni++)
            bfr[ni] = *(const short8*)&baseB[(fr*128 + wn + ni*16 + fc)*8];
        #pragma unroll
        for (int mi = 0; mi < 4; mi++)
            #pragma unroll
            for (int ni = 0; ni < 4; ni++)
                acc[mi][ni] = __builtin_amdgcn_mfma_f32_16x16x32_bf16(
                    af[mi], bfr[ni], acc[mi][ni], 0, 0, 0);
    }
    // D layout per 16x16 tile: row(m)=(lane>>4)*4+r, col(n)=lane&15
    #pragma unroll
    for (int mi = 0; mi < 4; mi++) {
        #pragma unroll
        for (int ni = 0; ni < 4; ni++) {
            int n = n0 + wn + ni*16 + fc;
            float bn_ = bias[n];
            float bm = 0.f, bs = 0.f, bb2 = 0.f;
            if (flags & FL_RESBN) { bm = ms[n]; bs = ms[CC + n]*bng[n]; bb2 = bnb[n]; }
            #pragma unroll
            for (int r = 0; r < 4; r++) {
                int m = m0 + wm + mi*16 + fr*4 + r;
                size_t idx2 = (size_t)m*ostride + n;
                float val = acc[mi][ni][r] + bn_;
                if (flags & FL_RESBN) val += (rx[idx2] - bm)*bs + bb2;
                if (flags & FL_RELU) val = fmaxf(val, 0.f);
                if (flags & FL_BF16) outb[idx2] = f2bf(val);
                else                 outf[idx2] = val;
            }
        }
    }
}

// ---------------------------------------------------------------------------
// Small fp32 GEMM (relay path)
__global__ __launch_bounds__(256) void k_sgemm(
    const float* __restrict__ W, const float* __restrict__ X,
    const float* __restrict__ bias, const float* __restrict__ res,
    float* __restrict__ out, int K, int OUT, int do_relu)
{
    __shared__ float sW[16][17];
    __shared__ float sX[16][17];
    int o0 = blockIdx.x*16, n0 = blockIdx.y*16;
    int tx = threadIdx.x, ty = threadIdx.y;
    int tid = ty*16 + tx;
    int cl = tid % 16, rl = tid / 16;
    float acc = 0.f;
    for (int kc = 0; kc < K; kc += 16) {
        sW[cl][rl] = W[(size_t)(o0 + rl)*K + kc + cl];
        sX[rl][cl] = (n0 + rl < NN) ? X[(size_t)(n0 + rl)*K + kc + cl] : 0.f;
        __syncthreads();
        #pragma unroll
        for (int kk = 0; kk < 16; kk++) acc += sW[kk][tx] * sX[ty][kk];
        __syncthreads();
    }
    int o = o0 + tx, n = n0 + ty;
    if (n < NN) {
        float val = acc + bias[o];
        if (res) val += res[(size_t)n*OUT + o];
        if (do_relu) val = fmaxf(val, 0.f);
        out[(size_t)n*OUT + o] = val;
    }
}

// ---------------------------------------------------------------------------
// tj attention, all token-major. qkv [nt][768] (q|k|v), ekv [nt][512] (ek|ev),
// rkv [n][512] f32, xln [nt][256] f32. out s1 [nt][256] f32.
__global__ __launch_bounds__(128) void k_attn_tj(
    const ushort_t* __restrict__ qkv, const ushort_t* __restrict__ ekv,
    const float* __restrict__ rkv, const float* __restrict__ xln,
    float* __restrict__ out)
{
    int t = threadIdx.x, h = blockIdx.x, n = blockIdx.y;
    int nt = n*TT + t;
    const ushort_t* qp = qkv + (size_t)nt*768 + h*32;
    const ushort_t* kp = qp + 256;
    const ushort_t* vp = qp + 512;
    const ushort_t* ep = ekv + (size_t)nt*512 + h*32;
    const float*    rp = rkv + n*512 + h*32;

    float qv[32];
    ld32(qp, qv);
    float s0 = 0.f, s1, s2 = 0.f, s3, s4 = 0.f;
    s1 = dot32(kp, qv);
    s3 = dot32(ep, qv);
    #pragma unroll
    for (int j = 0; j < 8; j++) {
        float4 rv4 = *(const float4*)&rp[j*4];
        s4 += qv[j*4]*rv4.x + qv[j*4+1]*rv4.y + qv[j*4+2]*rv4.z + qv[j*4+3]*rv4.w;
    }
    if (t > 0)    s0 = dot32(kp - 768, qv);
    if (t < TT-1) s2 = dot32(kp + 768, qv);

    s0 *= SCALE_F; s1 *= SCALE_F; s2 *= SCALE_F; s3 *= SCALE_F; s4 *= SCALE_F;
    float mx = fmaxf(fmaxf(fmaxf(s0, s1), fmaxf(s2, s3)), s4);
    float e0 = expf(s0-mx), e1 = expf(s1-mx), e2 = expf(s2-mx), e3 = expf(s3-mx), e4 = expf(s4-mx);
    float inv = 1.f/(e0+e1+e2+e3+e4);
    e0 *= inv; e1 *= inv; e2 *= inv; e3 *= inv; e4 *= inv;

    float av[32];
    #pragma unroll
    for (int d = 0; d < 32; d++) av[d] = 0.f;
    acc32(vp, e1, av);
    acc32(ep + 256, e3, av);
    if (t > 0)    acc32(vp - 768, e0, av);
    if (t < TT-1) acc32(vp + 768, e2, av);
    #pragma unroll
    for (int j = 0; j < 8; j++) {
        float4 rv4 = *(const float4*)&rp[256 + j*4];
        av[j*4] += e4*rv4.x; av[j*4+1] += e4*rv4.y; av[j*4+2] += e4*rv4.z; av[j*4+3] += e4*rv4.w;
    }
    const float* xp = xln + (size_t)nt*CC + h*32;
    float* op = out + (size_t)nt*CC + h*32;
    #pragma unroll
    for (int j = 0; j < 8; j++) {
        float4 xv = *(const float4*)&xp[j*4];
        float4 ov;
        ov.x = xv.x + av[j*4]; ov.y = xv.y + av[j*4+1];
        ov.z = xv.z + av[j*4+2]; ov.w = xv.w + av[j*4+3];
        *(float4*)&op[j*4] = ov;
    }
}

// ---------------------------------------------------------------------------
// BN stats over tokens, TM input. Stage 1: per-sequence partials.
__global__ __launch_bounds__(256) void k_bnstats_tm(const float* __restrict__ x,
    float* __restrict__ partial)
{
    __shared__ float lds[8][256];
    int w = threadIdx.x >> 6, lane = threadIdx.x & 63;
    size_t base = (size_t)blockIdx.x*TT*CC;
    float s[4] = {0,0,0,0}, ss[4] = {0,0,0,0};
    for (int tok = w; tok < TT; tok += 4) {
        float4 v = *(const float4*)&x[base + (size_t)tok*CC + lane*4];
        s[0] += v.x; s[1] += v.y; s[2] += v.z; s[3] += v.w;
        ss[0] += v.x*v.x; ss[1] += v.y*v.y; ss[2] += v.z*v.z; ss[3] += v.w*v.w;
    }
    #pragma unroll
    for (int j = 0; j < 4; j++) { lds[w][lane*4+j] = s[j]; lds[4+w][lane*4+j] = ss[j]; }
    __syncthreads();
    int c = threadIdx.x;
    float ps  = lds[0][c]+lds[1][c]+lds[2][c]+lds[3][c];
    float pss = lds[4][c]+lds[5][c]+lds[6][c]+lds[7][c];
    partial[blockIdx.x*512 + c] = ps;
    partial[blockIdx.x*512 + 256 + c] = pss;
}
// Stage 2: reduce 200 partials -> ms[c]=mean, ms[256+c]=rstd
__global__ __launch_bounds__(256) void k_bnfin(const float* __restrict__ partial,
    float* __restrict__ ms)
{
    int c = threadIdx.x;
    float s = 0.f, ss = 0.f;
    for (int b = 0; b < NN; b++) { s += partial[b*512 + c]; ss += partial[b*512 + 256 + c]; }
    float m = s / NT;
    float var = ss / NT - m*m; if (var < 0.f) var = 0.f;
    ms[c] = m; ms[CC + c] = rsqrtf(var + EPS_BN);
}

// BN apply, TM elementwise: f32 out (optional) + bf16 out
__global__ __launch_bounds__(256) void k_bn_apply_tm(const float* __restrict__ x,
    const float* __restrict__ ms, const float* __restrict__ g, const float* __restrict__ b,
    float* __restrict__ outf, ushort_t* __restrict__ outb, int leaky)
{
    size_t base = ((size_t)blockIdx.x*256 + threadIdx.x)*4;
    int c0 = (int)(base & (CC-1));
    float4 v  = *(const float4*)&x[base];
    float4 m4 = *(const float4*)&ms[c0];
    float4 r4 = *(const float4*)&ms[CC + c0];
    float4 g4 = *(const float4*)&g[c0];
    float4 b4 = *(const float4*)&b[c0];
    v.x = (v.x - m4.x)*r4.x*g4.x + b4.x;
    v.y = (v.y - m4.y)*r4.y*g4.y + b4.y;
    v.z = (v.z - m4.z)*r4.z*g4.z + b4.z;
    v.w = (v.w - m4.w)*r4.w*g4.w + b4.w;
    if (leaky) {
        v.x = v.x > 0.f ? v.x : SLOPE*v.x;
        v.y = v.y > 0.f ? v.y : SLOPE*v.y;
        v.z = v.z > 0.f ? v.z : SLOPE*v.z;
        v.w = v.w > 0.f ? v.w : SLOPE*v.w;
    }
    if (outf) *(float4*)&outf[base] = v;
    ushort_t o4[4] = {f2bf(v.x), f2bf(v.y), f2bf(v.z), f2bf(v.w)};
    *(short4_t*)&outb[base] = *(short4_t*)o4;
}

// final BN + leaky + transpose TM -> d_out [n][c][t]
__global__ __launch_bounds__(256) void k_bn_out_t(const float* __restrict__ x,
    const float* __restrict__ ms, const float* __restrict__ g, const float* __restrict__ b,
    float* __restrict__ out)
{
    __shared__ float tile[64][65];
    int nt0 = blockIdx.x*64, c0 = blockIdx.y*64;
    int w = threadIdx.x >> 6, lane = threadIdx.x & 63;
    int n = nt0 >> 7, t0 = nt0 & 127;
    #pragma unroll
    for (int it = 0; it < 16; it++) {
        int tok = it*4 + w, c = c0 + lane;
        float v = x[(size_t)(nt0 + tok)*CC + c];
        v = (v - ms[c])*ms[CC + c]*g[c] + b[c];
        v = v > 0.f ? v : SLOPE*v;
        tile[tok][lane] = v;
    }
    __syncthreads();
    #pragma unroll
    for (int it = 0; it < 16; it++) {
        int c_l = it*4 + w;
        out[(size_t)(n*CC + c0 + c_l)*TT + t0 + lane] = tile[lane][c_l];
    }
}

// BatchNorm over n only (relay path), x/out [N,C]
__global__ __launch_bounds__(64) void k_bn_relay(const float* __restrict__ x,
    float* __restrict__ out, const float* __restrict__ g, const float* __restrict__ b, int leaky)
{
    int c = blockIdx.x, tid = threadIdx.x;
    float s = 0.f, ss = 0.f;
    for (int n = tid; n < NN; n += 64) { float v = x[(size_t)n*CC + c]; s += v; ss += v*v; }
    for (int off = 32; off; off >>= 1) { s += __shfl_down(s, off); ss += __shfl_down(ss, off); }
    float S = __shfl(s, 0), SS = __shfl(ss, 0);
    float m = S / NN;
    float var = SS / NN - m*m; if (var < 0.f) var = 0.f;
    float rs = rsqrtf(var + EPS_BN);
    float gg = g[c]*rs, bb = b[c];
    for (int n = tid; n < NN; n += 64) {
        float v = (x[(size_t)n*CC + c] - m)*gg + bb;
        if (leaky) v = v > 0.f ? v : SLOPE*v;
        out[(size_t)n*CC + c] = v;
    }
}

// ---------------------------------------------------------------------------
// relay cross-attention; ykv TM f32 [nt][512] (k|v); rkvY [n][512]
__global__ __launch_bounds__(64) void k_attn_tr(
    const float* __restrict__ rq, const float* __restrict__ ykv,
    const float* __restrict__ rkvY, const float* __restrict__ relay,
    float* __restrict__ out)
{
    int h = blockIdx.x, n = blockIdx.y, tid = threadIdx.x;
    __shared__ float sc[LL1];
    __shared__ float red[64][33];
    float q0[32];
    const float* qp = rq + (size_t)n*CC + h*32;
    #pragma unroll
    for (int j = 0; j < 8; j++) {
        float4 v = *(const float4*)&qp[j*4];
        q0[j*4] = v.x; q0[j*4+1] = v.y; q0[j*4+2] = v.z; q0[j*4+3] = v.w;
    }
    for (int l = tid; l < LL1; l += 64) {
        const float* kp = (l == 0) ? (rkvY + n*512 + h*32)
                                   : (ykv + (size_t)(n*TT + l-1)*512 + h*32);
        float s = 0.f;
        #pragma unroll
        for (int j = 0; j < 8; j++) {
            float4 v = *(const float4*)&kp[j*4];
            s += q0[j*4]*v.x + q0[j*4+1]*v.y + q0[j*4+2]*v.z + q0[j*4+3]*v.w;
        }
        sc[l] = s * SCALE_F;
    }
    __syncthreads();
    float mx = -1e30f;
    for (int l = tid; l < LL1; l += 64) mx = fmaxf(mx, sc[l]);
    for (int off = 32; off; off >>= 1) mx = fmaxf(mx, __shfl_xor(mx, off));
    float sum = 0.f;
    for (int l = tid; l < LL1; l += 64) { float e = expf(sc[l]-mx); sc[l] = e; sum += e; }
    for (int off = 32; off; off >>= 1) sum += __shfl_xor(sum, off);
    __syncthreads();
    float av[32];
    #pragma unroll
    for (int d = 0; d < 32; d++) av[d] = 0.f;
    for (int l = tid; l < LL1; l += 64) {
        float e = sc[l];
        const float* vp = (l == 0) ? (rkvY + n*512 + 256 + h*32)
                                   : (ykv + (size_t)(n*TT + l-1)*512 + 256 + h*32);
        #pragma unroll
        for (int j = 0; j < 8; j++) {
            float4 v = *(const float4*)&vp[j*4];
            av[j*4] += e*v.x; av[j*4+1] += e*v.y; av[j*4+2] += e*v.z; av[j*4+3] += e*v.w;
        }
    }
    #pragma unroll
    for (int d = 0; d < 32; d++) red[tid][d] = av[d];
    __syncthreads();
    if (tid < 32) {
        float a = 0.f;
        for (int k = 0; k < 64; k++) a += red[k][tid];
        a /= sum;
        int idx = n*CC + h*32 + tid;
        out[idx] = relay[idx] + a;
    }
}

// ---------------------------------------------------------------------------
extern "C" void kernel_launch(void* const* d_in, const int* in_sizes, int n_in,
                              void* d_out, int out_size, void* d_ws, size_t ws_size,
                              hipStream_t stream)
{
    const float* data    = (const float*)d_in[0];
    const float* ln_g    = (const float*)d_in[1];
    const float* ln_b    = (const float*)d_in[2];
    const float* tj_wq   = (const float*)d_in[3];
    const float* tj_bq   = (const float*)d_in[4];
    const float* tj_wk   = (const float*)d_in[5];
    const float* tj_bk   = (const float*)d_in[6];
    const float* tj_wv   = (const float*)d_in[7];
    const float* tj_bv   = (const float*)d_in[8];
    const float* tj_bn_g = (const float*)d_in[9];
    const float* tj_bn_b = (const float*)d_in[10];
    const float* tj_w1   = (const float*)d_in[11];
    const float* tj_b1   = (const float*)d_in[12];
    const float* tj_w2   = (const float*)d_in[13];
    const float* tj_b2   = (const float*)d_in[14];
    const float* tj_fbn_g= (const float*)d_in[15];
    const float* tj_fbn_b= (const float*)d_in[16];
    const float* tr_wq   = (const float*)d_in[17];
    const float* tr_bq   = (const float*)d_in[18];
    const float* tr_wk   = (const float*)d_in[19];
    const float* tr_bk   = (const float*)d_in[20];
    const float* tr_wv   = (const float*)d_in[21];
    const float* tr_bv   = (const float*)d_in[22];
    const float* tr_bn_g = (const float*)d_in[23];
    const float* tr_bn_b = (const float*)d_in[24];
    const float* tr_w1   = (const float*)d_in[25];
    const float* tr_b1   = (const float*)d_in[26];
    const float* tr_w2   = (const float*)d_in[27];
    const float* tr_b2   = (const float*)d_in[28];
    const float* tr_fbn_g= (const float*)d_in[29];
    const float* tr_fbn_b= (const float*)d_in[30];

    const size_t SZ = (size_t)NT*CC;     // 6,553,600
    const size_t SZ_NC = (size_t)NN*CC;

    // ws ~158 MB (R3's 167 passed)
    float* ws = (float*)d_ws;
    size_t off = 0;
    auto alloc = [&](size_t nf) { float* p = ws + off; off += nf; return p; };
    float*    nodesf  = alloc(SZ);          // TM f32; LN in-place (holds xln)
    float*    sbuf    = alloc(SZ);          // TM f32: s1 / s1b (FFN2 in-place)
    float*    P1      = alloc(SZ*5/2);      // qkv(1.5)+ekv(1.0) bf16 | h(2.0) bf16 | ykv(2.0) f32
    ushort_t* xs_bf   = (ushort_t*)alloc(SZ/2);  // xln_bf -> s2_bf -> nodes_bf (TM)
    ushort_t* embs_bf = (ushort_t*)alloc(SZ/2);  // TM, persists
    float* partial = alloc((size_t)NN*512);
    float* msA    = alloc(2*CC);
    float* msB    = alloc(2*CC);
    float* relayA = alloc(SZ_NC);
    float* relayB = alloc(SZ_NC);
    float* rkv    = alloc(2*SZ_NC);
    float* rkvY   = alloc(2*SZ_NC);
    float* rq_    = alloc(SZ_NC);
    float* ret0   = alloc(SZ_NC);
    float* rret   = alloc(SZ_NC);
    float* ro     = alloc(SZ_NC);
    float* rh     = alloc((size_t)NN*DFFF);
    ushort_t* wqkv_bf  = (ushort_t*)alloc((size_t)ITER*768*CC/2);
    ushort_t* wkvtr_bf = (ushort_t*)alloc((size_t)ITER*512*CC/2);
    ushort_t* w1_bf    = (ushort_t*)alloc((size_t)ITER*DFFF*CC/2);
    ushort_t* w2_bf    = (ushort_t*)alloc((size_t)ITER*DFFF*CC/2);
    float* wkvtj_f = alloc((size_t)ITER*512*CC);
    float* wkvtr_f = alloc((size_t)ITER*512*CC);
    float* bqkv    = alloc((size_t)ITER*768);
    float* bkvtr   = alloc((size_t)ITER*512);
    (void)ws_size; (void)in_sizes; (void)n_in; (void)out_size;

    ushort_t* qkv_tm = (ushort_t*)P1;           // [nt][768] bf16
    ushort_t* ekv_tm = qkv_tm + 3*SZ;           // [nt][512] bf16
    ushort_t* h_us   = (ushort_t*)P1;           // [nt][1024] bf16 (after attn)
    float*    ykv_f  = P1;                      // [nt][512] f32 (after FFN2)

    const int TCC = ITER*CC*CC, TFF = ITER*DFFF*CC;
    k_cast2<<<(TCC+255)/256, 256, 0, stream>>>(tj_wq, wqkv_bf,          65536, 196608, TCC);
    k_cast2<<<(TCC+255)/256, 256, 0, stream>>>(tj_wk, wqkv_bf +  65536, 65536, 196608, TCC);
    k_cast2<<<(TCC+255)/256, 256, 0, stream>>>(tj_wv, wqkv_bf + 131072, 65536, 196608, TCC);
    k_cast2<<<(TCC+255)/256, 256, 0, stream>>>(tr_wk, wkvtr_bf,         65536, 131072, TCC);
    k_cast2<<<(TCC+255)/256, 256, 0, stream>>>(tr_wv, wkvtr_bf + 65536, 65536, 131072, TCC);
    k_cast2<<<(TFF+255)/256, 256, 0, stream>>>(tj_w1, w1_bf, TFF, TFF, TFF);
    k_cast2<<<(TFF+255)/256, 256, 0, stream>>>(tj_w2, w2_bf, TFF, TFF, TFF);
    k_copy2<<<(ITER*256+255)/256, 256, 0, stream>>>(tj_bq, bqkv,       256, 768, ITER*256);
    k_copy2<<<(ITER*256+255)/256, 256, 0, stream>>>(tj_bk, bqkv + 256, 256, 768, ITER*256);
    k_copy2<<<(ITER*256+255)/256, 256, 0, stream>>>(tj_bv, bqkv + 512, 256, 768, ITER*256);
    k_copy2<<<(ITER*256+255)/256, 256, 0, stream>>>(tr_bk, bkvtr,      256, 512, ITER*256);
    k_copy2<<<(ITER*256+255)/256, 256, 0, stream>>>(tr_bv, bkvtr+256,  256, 512, ITER*256);
    k_copy2<<<(TCC+255)/256, 256, 0, stream>>>(tj_wk, wkvtj_f,         65536, 131072, TCC);
    k_copy2<<<(TCC+255)/256, 256, 0, stream>>>(tj_wv, wkvtj_f + 65536, 65536, 131072, TCC);
    k_copy2<<<(TCC+255)/256, 256, 0, stream>>>(tr_wk, wkvtr_f,         65536, 131072, TCC);
    k_copy2<<<(TCC+255)/256, 256, 0, stream>>>(tr_wv, wkvtr_f + 65536, 65536, 131072, TCC);

    k_embed<<<dim3(8, NN), 128, 0, stream>>>(data, nodesf, embs_bf, relayA);

    float* relay = relayA;
    float* relay_next = relayB;
    dim3 sb16(16, 16);

    for (int i = 0; i < ITER; i++) {
        const size_t wo768 = (size_t)i*768*CC;
        const size_t wo512 = (size_t)i*512*CC;
        const size_t woff  = (size_t)i*DFFF*CC;

        k_layernorm<<<NT/4, 256, 0, stream>>>(nodesf, xs_bf, ln_g + i*CC, ln_b + i*CC);

        // qkv: [nt][768] bf16  (grid = 200 m-tiles x 6 n-tiles, XCD-swizzled)
        k_gemm_mfma<<<200*6, 256, 0, stream>>>(
            xs_bf, wqkv_bf + wo768, bqkv + i*768, nullptr, nullptr, nullptr, nullptr,
            nullptr, qkv_tm, CC, 768, 6, FL_BF16);
        // ekv: [nt][512] bf16 (weight rows 256..767)
        k_gemm_mfma<<<200*4, 256, 0, stream>>>(
            embs_bf, wqkv_bf + wo768 + 65536, bqkv + i*768 + 256, nullptr, nullptr, nullptr, nullptr,
            nullptr, ekv_tm, CC, 512, 4, FL_BF16);
        // relay k|v f32 [n][512]
        k_sgemm<<<dim3(32, (NN+15)/16), sb16, 0, stream>>>(
            wkvtj_f + wo512, relay, bqkv + i*768 + 256, nullptr, rkv, CC, 512, 0);

        k_attn_tj<<<dim3(NHH, NN), 128, 0, stream>>>(qkv_tm, ekv_tm, rkv, nodesf, sbuf);

        k_bnstats_tm<<<NN, 256, 0, stream>>>(sbuf, partial);
        k_bnfin<<<1, 256, 0, stream>>>(partial, msA);
        // BN1 apply -> s2_bf only (FFN2 recomputes BN1(s1) in epilogue)
        k_bn_apply_tm<<<SZ/1024, 256, 0, stream>>>(
            sbuf, msA, tj_bn_g + i*CC, tj_bn_b + i*CC, nullptr, xs_bf, 0);

        // FFN1: h = relu(W1*s2+b1), [nt][1024] bf16
        k_gemm_mfma<<<200*8, 256, 0, stream>>>(
            xs_bf, w1_bf + woff, tj_b1 + i*DFFF, nullptr, nullptr, nullptr, nullptr,
            nullptr, h_us, CC, DFFF, 8, FL_RELU | FL_BF16);
        // FFN2: sbuf = W2*h + b2 + BN1(sbuf)   (in-place, per-thread idx safe)
        k_gemm_mfma<<<200*2, 256, 0, stream>>>(
            h_us, w2_bf + woff, tj_b2 + i*CC, sbuf, msA, tj_bn_g + i*CC, tj_bn_b + i*CC,
            sbuf, nullptr, DFFF, CC, 2, FL_RESBN);

        k_bnstats_tm<<<NN, 256, 0, stream>>>(sbuf, partial);
        k_bnfin<<<1, 256, 0, stream>>>(partial, msB);
        if (i == ITER-1) {
            k_bn_out_t<<<dim3(NT/64, CC/64), 256, 0, stream>>>(
                sbuf, msB, tj_fbn_g + i*CC, tj_fbn_b + i*CC, (float*)d_out);
            break;   // last relay update is dead code
        }
        // nodes = leaky(BN2(sbuf)) -> nodesf f32 + xs_bf bf16
        k_bn_apply_tm<<<SZ/1024, 256, 0, stream>>>(
            sbuf, msB, tj_fbn_g + i*CC, tj_fbn_b + i*CC, nodesf, xs_bf, 1);

        // relay path: ykv = W_kv^tr * nodes, [nt][512] f32
        k_gemm_mfma<<<200*4, 256, 0, stream>>>(
            xs_bf, wkvtr_bf + wo512, bkvtr + i*512, nullptr, nullptr, nullptr, nullptr,
            ykv_f, nullptr, CC, 512, 4, 0);
        k_sgemm<<<dim3(16, (NN+15)/16), sb16, 0, stream>>>(
            tr_wq + (size_t)i*CC*CC, relay, tr_bq + i*CC, nullptr, rq_, CC, CC, 0);
        k_sgemm<<<dim3(32, (NN+15)/16), sb16, 0, stream>>>(
            wkvtr_f + wo512, relay, bkvtr + i*512, nullptr, rkvY, CC, 512, 0);

        k_attn_tr<<<dim3(NHH, NN), 64, 0, stream>>>(rq_, ykv_f, rkvY, relay, ret0);
        k_bn_relay<<<CC, 64, 0, stream>>>(ret0, rret, tr_bn_g + i*CC, tr_bn_b + i*CC, 0);

        k_sgemm<<<dim3(DFFF/16, (NN+15)/16), sb16, 0, stream>>>(
            tr_w1 + woff, rret, tr_b1 + i*DFFF, nullptr, rh, CC, DFFF, 1);
        k_sgemm<<<dim3(16, (NN+15)/16), sb16, 0, stream>>>(
            tr_w2 + woff, rh, tr_b2 + i*CC, rret, ro, DFFF, CC, 0);
        k_bn_relay<<<CC, 64, 0, stream>>>(ro, relay_next, tr_fbn_g + i*CC, tr_fbn_b + i*CC, 1);

        float* tmp = relay; relay = relay_next; relay_next = tmp;
    }
}

// Round 7
// 1496.333 us; speedup vs baseline: 1.1784x; 1.1784x over previous
//
#include <hip/hip_runtime.h>
#include <cstddef>

#define BB   8
#define VV   25
#define TT   128
#define CC   256
#define NHH  8
#define DKK  32
#define DFFF 1024
#define ITER 4
#define NN   (BB*VV)     // 200
#define NT   (NN*TT)     // 25600
#define LL1  (TT+1)      // 129
#define EPS_LN 1e-6f
#define EPS_BN 1e-5f
#define SLOPE  0.01f
#define SCALE_F 0.17677669529663687f   // 1/sqrt(32)

typedef unsigned short ushort_t;
typedef __attribute__((ext_vector_type(8))) short short8;
typedef __attribute__((ext_vector_type(4))) short short4_t;
typedef __attribute__((ext_vector_type(4))) float floatx4;

union U8 { short8 v; ushort_t u[8]; };

__device__ __forceinline__ float bf2f(ushort_t u) {
    union { unsigned int i; float f; } x; x.i = ((unsigned int)u) << 16; return x.f;
}
__device__ __forceinline__ ushort_t f2bf(float f) {
    union { float f; unsigned int i; } x; x.f = f;
    unsigned int r = x.i + 0x7FFFu + ((x.i >> 16) & 1u);   // RNE
    return (ushort_t)(r >> 16);
}
// finalize raw BN sums -> (mean, rstd)
__device__ __forceinline__ float2 bn_fin(float s, float ss) {
    float m = s * (1.0f/NT);
    float var = ss * (1.0f/NT) - m*m; if (var < 0.f) var = 0.f;
    return make_float2(m, rsqrtf(var + EPS_BN));
}

// load 32 bf16 (contiguous) -> f32 regs
__device__ __forceinline__ void ld32(const ushort_t* p, float* q) {
    #pragma unroll
    for (int c8 = 0; c8 < 4; c8++) {
        U8 u; u.v = *(const short8*)(p + c8*8);
        #pragma unroll
        for (int j = 0; j < 8; j++) q[c8*8+j] = bf2f(u.u[j]);
    }
}
__device__ __forceinline__ float dot32(const ushort_t* p, const float* q) {
    float s = 0.f;
    #pragma unroll
    for (int c8 = 0; c8 < 4; c8++) {
        U8 u; u.v = *(const short8*)(p + c8*8);
        #pragma unroll
        for (int j = 0; j < 8; j++) s += q[c8*8+j]*bf2f(u.u[j]);
    }
    return s;
}
__device__ __forceinline__ void acc32(const ushort_t* p, float e, float* av) {
    #pragma unroll
    for (int c8 = 0; c8 < 4; c8++) {
        U8 u; u.v = *(const short8*)(p + c8*8);
        #pragma unroll
        for (int j = 0; j < 8; j++) av[c8*8+j] += e*bf2f(u.u[j]);
    }
}

// ---------------------------------------------------------------------------
__global__ __launch_bounds__(256) void k_zero(float* __restrict__ p, int n)
{
    int i = blockIdx.x*256 + threadIdx.x;
    if (i < n) p[i] = 0.f;
}
// strided cast/copy: dst[(i/per)*dstride + i%per] = src[i]
__global__ __launch_bounds__(256) void k_cast2(const float* __restrict__ src,
    ushort_t* __restrict__ dst, int per, int dstride, int total)
{
    int i = blockIdx.x*256 + threadIdx.x;
    if (i < total) dst[(size_t)(i/per)*dstride + (i%per)] = f2bf(src[i]);
}
__global__ __launch_bounds__(256) void k_copy2(const float* __restrict__ src,
    float* __restrict__ dst, int per, int dstride, int total)
{
    int i = blockIdx.x*256 + threadIdx.x;
    if (i < total) dst[(size_t)(i/per)*dstride + (i%per)] = src[i];
}

// ---------------------------------------------------------------------------
// embed: nodesf[nt][c] f32 TM + embs_bf TM + relay[n][c]=mean_t. LDS transpose.
__global__ __launch_bounds__(128) void k_embed(const float* __restrict__ data,
    float* __restrict__ nodesf, ushort_t* __restrict__ embs_bf, float* __restrict__ relay)
{
    __shared__ float tile[32][TT+1];
    int cc0 = blockIdx.x*32, n = blockIdx.y;
    int b = n / VV, v = n % VV, t = threadIdx.x;
    for (int cl = 0; cl < 32; cl++)
        tile[cl][t] = data[(((size_t)b*CC + cc0 + cl)*VV + v)*TT + t];
    __syncthreads();
    if (t < 32) {
        float s = 0.f;
        for (int tt = 0; tt < TT; tt++) s += tile[t][tt];
        relay[n*CC + cc0 + t] = s * (1.0f/TT);
    }
    #pragma unroll 8
    for (int it = 0; it < 32; it++) {
        int t_l = it*4 + (t >> 5), c_l = t & 31;
        float val = tile[c_l][t_l];
        size_t o = (size_t)(n*TT + t_l)*CC + cc0 + c_l;
        nodesf[o] = val;
        embs_bf[o] = f2bf(val);
    }
}

// ---------------------------------------------------------------------------
// LayerNorm TM in-place + bf16 TM copy. One wave per token. (layer 0 only)
__global__ __launch_bounds__(256) void k_layernorm(float* __restrict__ x,
    ushort_t* __restrict__ outb, const float* __restrict__ g, const float* __restrict__ b)
{
    int wave = threadIdx.x >> 6, lane = threadIdx.x & 63;
    size_t base = (size_t)(blockIdx.x*4 + wave)*CC + lane*4;
    float4 v = *(float4*)&x[base];
    float s  = v.x + v.y + v.z + v.w;
    float ss = v.x*v.x + v.y*v.y + v.z*v.z + v.w*v.w;
    #pragma unroll
    for (int o = 32; o; o >>= 1) { s += __shfl_xor(s, o); ss += __shfl_xor(ss, o); }
    float m = s * (1.0f/CC);
    float var = ss * (1.0f/CC) - m*m; if (var < 0.f) var = 0.f;
    float rs = rsqrtf(var + EPS_LN);
    float4 gg = *(const float4*)&g[lane*4];
    float4 bb = *(const float4*)&b[lane*4];
    v.x = (v.x - m)*rs*gg.x + bb.x;
    v.y = (v.y - m)*rs*gg.y + bb.y;
    v.z = (v.z - m)*rs*gg.z + bb.z;
    v.w = (v.w - m)*rs*gg.w + bb.w;
    *(float4*)&x[base] = v;
    ushort_t o4[4] = {f2bf(v.x), f2bf(v.y), f2bf(v.z), f2bf(v.w)};
    *(short4_t*)&outb[base] = *(short4_t*)o4;
}

// ---------------------------------------------------------------------------
// bf16 MFMA GEMM, token-major (R5-proven core: VGPR staging, 2 barriers,
// stride-48 LDS) + XCD swizzle (pid&7 = xcd owns 25 m-tiles; A fetched by
// exactly one XCD). D[m=token][n=outch] = act(A·B + bias[n] (+BN(res))).
// FL_RESBN finalizes raw BN sums (rawms[n]=sum, rawms[CC+n]=sumsq) inline.
#define FL_RELU  1
#define FL_BF16  2
#define FL_RESBN 4
__global__ __launch_bounds__(256) void k_gemm_mfma(
    const ushort_t* __restrict__ A, const ushort_t* __restrict__ B,
    const float* __restrict__ bias,
    const float* rx, const float* __restrict__ rawms,
    const float* __restrict__ bng, const float* __restrict__ bnb,
    float* outf, ushort_t* __restrict__ outb,
    int K, int ostride, int ntiles_n, int flags)
{
    __shared__ ushort_t sA[128*48];
    __shared__ ushort_t sB[128*48];
    const int pid = blockIdx.x;
    const int xcd = pid & 7, idx = pid >> 3;
    const int n0 = (idx % ntiles_n) * 128;
    const int m0 = (xcd*25 + idx/ntiles_n) * 128;   // 200 m-tiles = 8 XCD x 25
    const int tid = threadIdx.x;
    const int lane = tid & 63, wave = tid >> 6;
    const int wm = (wave & 1) * 64, wn = (wave >> 1) * 64;
    const int fr = lane >> 4, fc = lane & 15;

    floatx4 acc[4][4];
    #pragma unroll
    for (int i = 0; i < 4; i++)
        #pragma unroll
        for (int j = 0; j < 4; j++) acc[i][j] = (floatx4){0.f,0.f,0.f,0.f};

    for (int kc = 0; kc < K; kc += 32) {
        #pragma unroll
        for (int it = 0; it < 2; it++) {
            int task = tid + it*256;
            int row = task >> 2, ch = task & 3;
            *(short8*)&sA[row*48 + ch*8] =
                *(const short8*)&A[(size_t)(m0 + row)*K + kc + ch*8];
            *(short8*)&sB[row*48 + ch*8] =
                *(const short8*)&B[(size_t)(n0 + row)*K + kc + ch*8];
        }
        __syncthreads();
        short8 af[4], bfr[4];
        #pragma unroll
        for (int mi = 0; mi < 4; mi++)
            af[mi] = *(const short8*)&sA[(wm + mi*16 + fc)*48 + fr*8];
        #pragma unroll
        for (int ni = 0; ni < 4; ni++)
            bfr[ni] = *(const short8*)&sB[(wn + ni*16 + fc)*48 + fr*8];
        #pragma unroll
        for (int mi = 0; mi < 4; mi++)
            #pragma unroll
            for (int ni = 0; ni < 4; ni++)
                acc[mi][ni] = __builtin_amdgcn_mfma_f32_16x16x32_bf16(
                    af[mi], bfr[ni], acc[mi][ni], 0, 0, 0);
        __syncthreads();
    }
    // D layout per 16x16 tile: row(m)=(lane>>4)*4+r, col(n)=lane&15
    #pragma unroll
    for (int mi = 0; mi < 4; mi++) {
        #pragma unroll
        for (int ni = 0; ni < 4; ni++) {
            int n = n0 + wn + ni*16 + fc;
            float bn_ = bias[n];
            float bm = 0.f, bs = 0.f, bb2 = 0.f;
            if (flags & FL_RESBN) {
                float2 f = bn_fin(rawms[n], rawms[CC + n]);
                bm = f.x; bs = f.y*bng[n]; bb2 = bnb[n];
            }
            #pragma unroll
            for (int r = 0; r < 4; r++) {
                int m = m0 + wm + mi*16 + fr*4 + r;
                size_t idx2 = (size_t)m*ostride + n;
                float val = acc[mi][ni][r] + bn_;
                if (flags & FL_RESBN) val += (rx[idx2] - bm)*bs + bb2;
                if (flags & FL_RELU) val = fmaxf(val, 0.f);
                if (flags & FL_BF16) outb[idx2] = f2bf(val);
                else                 outf[idx2] = val;
            }
        }
    }
}

// ---------------------------------------------------------------------------
// Small fp32 GEMM (relay path)
__global__ __launch_bounds__(256) void k_sgemm(
    const float* __restrict__ W, const float* __restrict__ X,
    const float* __restrict__ bias, const float* __restrict__ res,
    float* __restrict__ out, int K, int OUT, int do_relu)
{
    __shared__ float sW[16][17];
    __shared__ float sX[16][17];
    int o0 = blockIdx.x*16, n0 = blockIdx.y*16;
    int tx = threadIdx.x, ty = threadIdx.y;
    int tid = ty*16 + tx;
    int cl = tid % 16, rl = tid / 16;
    float acc = 0.f;
    for (int kc = 0; kc < K; kc += 16) {
        sW[cl][rl] = W[(size_t)(o0 + rl)*K + kc + cl];
        sX[rl][cl] = (n0 + rl < NN) ? X[(size_t)(n0 + rl)*K + kc + cl] : 0.f;
        __syncthreads();
        #pragma unroll
        for (int kk = 0; kk < 16; kk++) acc += sW[kk][tx] * sX[ty][kk];
        __syncthreads();
    }
    int o = o0 + tx, n = n0 + ty;
    if (n < NN) {
        float val = acc + bias[o];
        if (res) val += res[(size_t)n*OUT + o];
        if (do_relu) val = fmaxf(val, 0.f);
        out[(size_t)n*OUT + o] = val;
    }
}

// ---------------------------------------------------------------------------
// tj attention, token-major. qkv [nt][768] (q|k|v), ekv [nt][512] (ek|ev),
// rel [n][1280] f32 (tj_k|tj_v|tr_k|tr_v|tr_q), xln [nt][256] f32.
__global__ __launch_bounds__(128) void k_attn_tj(
    const ushort_t* __restrict__ qkv, const ushort_t* __restrict__ ekv,
    const float* __restrict__ rel, const float* __restrict__ xln,
    float* __restrict__ out)
{
    int t = threadIdx.x, h = blockIdx.x, n = blockIdx.y;
    int nt = n*TT + t;
    const ushort_t* qp = qkv + (size_t)nt*768 + h*32;
    const ushort_t* kp = qp + 256;
    const ushort_t* vp = qp + 512;
    const ushort_t* ep = ekv + (size_t)nt*512 + h*32;
    const float*    rp = rel + n*1280 + h*32;   // k at +0, v at +256

    float qv[32];
    ld32(qp, qv);
    float s0 = 0.f, s1, s2 = 0.f, s3, s4 = 0.f;
    s1 = dot32(kp, qv);
    s3 = dot32(ep, qv);
    #pragma unroll
    for (int j = 0; j < 8; j++) {
        float4 rv4 = *(const float4*)&rp[j*4];
        s4 += qv[j*4]*rv4.x + qv[j*4+1]*rv4.y + qv[j*4+2]*rv4.z + qv[j*4+3]*rv4.w;
    }
    if (t > 0)    s0 = dot32(kp - 768, qv);
    if (t < TT-1) s2 = dot32(kp + 768, qv);

    s0 *= SCALE_F; s1 *= SCALE_F; s2 *= SCALE_F; s3 *= SCALE_F; s4 *= SCALE_F;
    float mx = fmaxf(fmaxf(fmaxf(s0, s1), fmaxf(s2, s3)), s4);
    float e0 = expf(s0-mx), e1 = expf(s1-mx), e2 = expf(s2-mx), e3 = expf(s3-mx), e4 = expf(s4-mx);
    float inv = 1.f/(e0+e1+e2+e3+e4);
    e0 *= inv; e1 *= inv; e2 *= inv; e3 *= inv; e4 *= inv;

    float av[32];
    #pragma unroll
    for (int d = 0; d < 32; d++) av[d] = 0.f;
    acc32(vp, e1, av);
    acc32(ep + 256, e3, av);
    if (t > 0)    acc32(vp - 768, e0, av);
    if (t < TT-1) acc32(vp + 768, e2, av);
    #pragma unroll
    for (int j = 0; j < 8; j++) {
        float4 rv4 = *(const float4*)&rp[256 + j*4];
        av[j*4] += e4*rv4.x; av[j*4+1] += e4*rv4.y; av[j*4+2] += e4*rv4.z; av[j*4+3] += e4*rv4.w;
    }
    const float* xp = xln + (size_t)nt*CC + h*32;
    float* op = out + (size_t)nt*CC + h*32;
    #pragma unroll
    for (int j = 0; j < 8; j++) {
        float4 xv = *(const float4*)&xp[j*4];
        float4 ov;
        ov.x = xv.x + av[j*4]; ov.y = xv.y + av[j*4+1];
        ov.z = xv.z + av[j*4+2]; ov.w = xv.w + av[j*4+3];
        *(float4*)&op[j*4] = ov;
    }
}

// ---------------------------------------------------------------------------
// BN stats over tokens, TM input; atomicAdd raw sums into accum[512]
// (accum must be zeroed earlier in this launch).
__global__ __launch_bounds__(256) void k_bnstats_tm(const float* __restrict__ x,
    float* __restrict__ accum)
{
    __shared__ float lds[8][256];
    int w = threadIdx.x >> 6, lane = threadIdx.x & 63;
    size_t base = (size_t)blockIdx.x*TT*CC;
    float s[4] = {0,0,0,0}, ss[4] = {0,0,0,0};
    for (int tok = w; tok < TT; tok += 4) {
        float4 v = *(const float4*)&x[base + (size_t)tok*CC + lane*4];
        s[0] += v.x; s[1] += v.y; s[2] += v.z; s[3] += v.w;
        ss[0] += v.x*v.x; ss[1] += v.y*v.y; ss[2] += v.z*v.z; ss[3] += v.w*v.w;
    }
    #pragma unroll
    for (int j = 0; j < 4; j++) { lds[w][lane*4+j] = s[j]; lds[4+w][lane*4+j] = ss[j]; }
    __syncthreads();
    int c = threadIdx.x;
    float ps  = lds[0][c]+lds[1][c]+lds[2][c]+lds[3][c];
    float pss = lds[4][c]+lds[5][c]+lds[6][c]+lds[7][c];
    atomicAdd(&accum[c], ps);
    atomicAdd(&accum[CC + c], pss);
}

// BN1 apply (no leaky), raw sums, bf16 TM out only
__global__ __launch_bounds__(256) void k_bn_apply_raw(const float* __restrict__ x,
    const float* __restrict__ acc, const float* __restrict__ g, const float* __restrict__ b,
    ushort_t* __restrict__ outb)
{
    size_t base = ((size_t)blockIdx.x*256 + threadIdx.x)*4;
    int c0 = (int)(base & (CC-1));
    float4 v  = *(const float4*)&x[base];
    float4 a1 = *(const float4*)&acc[c0];
    float4 a2 = *(const float4*)&acc[CC + c0];
    float4 g4 = *(const float4*)&g[c0];
    float4 b4 = *(const float4*)&b[c0];
    float vals[4] = {v.x,v.y,v.z,v.w};
    float s1v[4] = {a1.x,a1.y,a1.z,a1.w};
    float s2v[4] = {a2.x,a2.y,a2.z,a2.w};
    float gg[4] = {g4.x,g4.y,g4.z,g4.w};
    float bb[4] = {b4.x,b4.y,b4.z,b4.w};
    ushort_t o4[4];
    #pragma unroll
    for (int j = 0; j < 4; j++) {
        float2 f = bn_fin(s1v[j], s2v[j]);
        o4[j] = f2bf((vals[j] - f.x)*f.y*gg[j] + bb[j]);
    }
    *(short4_t*)&outb[base] = *(short4_t*)o4;
}

// Fused BN2 + leaky + next-layer LN. Outputs: nodes_bf (pre-LN bf16, for ykv
// GEMM), xln f32 (attn residual), xln bf16 (qkv GEMM input). One wave/token.
__global__ __launch_bounds__(256) void k_bn_ln(const float* __restrict__ x,
    const float* __restrict__ acc, const float* __restrict__ fg, const float* __restrict__ fb,
    const float* __restrict__ lg, const float* __restrict__ lb,
    float* __restrict__ xlnf, ushort_t* __restrict__ xlnb, ushort_t* __restrict__ nodesb)
{
    int wave = threadIdx.x >> 6, lane = threadIdx.x & 63;
    int c0 = lane*4;
    size_t base = (size_t)(blockIdx.x*4 + wave)*CC + c0;
    float4 v  = *(const float4*)&x[base];
    float4 a1 = *(const float4*)&acc[c0];
    float4 a2 = *(const float4*)&acc[CC + c0];
    float4 g4 = *(const float4*)&fg[c0];
    float4 b4 = *(const float4*)&fb[c0];
    float vals[4] = {v.x,v.y,v.z,v.w};
    float s1v[4] = {a1.x,a1.y,a1.z,a1.w};
    float s2v[4] = {a2.x,a2.y,a2.z,a2.w};
    float gg[4] = {g4.x,g4.y,g4.z,g4.w};
    float bb[4] = {b4.x,b4.y,b4.z,b4.w};
    ushort_t nb4[4];
    #pragma unroll
    for (int j = 0; j < 4; j++) {
        float2 f = bn_fin(s1v[j], s2v[j]);
        float vv = (vals[j] - f.x)*f.y*gg[j] + bb[j];
        vv = vv > 0.f ? vv : SLOPE*vv;
        vals[j] = vv;
        nb4[j] = f2bf(vv);
    }
    *(short4_t*)&nodesb[base] = *(short4_t*)nb4;
    // LN over the token (wave = 1 token)
    float s  = vals[0]+vals[1]+vals[2]+vals[3];
    float ss = vals[0]*vals[0]+vals[1]*vals[1]+vals[2]*vals[2]+vals[3]*vals[3];
    #pragma unroll
    for (int o = 32; o; o >>= 1) { s += __shfl_xor(s, o); ss += __shfl_xor(ss, o); }
    float m = s * (1.0f/CC);
    float var = ss * (1.0f/CC) - m*m; if (var < 0.f) var = 0.f;
    float rs = rsqrtf(var + EPS_LN);
    float4 lg4 = *(const float4*)&lg[c0];
    float4 lb4 = *(const float4*)&lb[c0];
    float lgv[4] = {lg4.x,lg4.y,lg4.z,lg4.w};
    float lbv[4] = {lb4.x,lb4.y,lb4.z,lb4.w};
    float4 xo;
    ushort_t xb4[4];
    float t0 = (vals[0]-m)*rs*lgv[0] + lbv[0];
    float t1 = (vals[1]-m)*rs*lgv[1] + lbv[1];
    float t2 = (vals[2]-m)*rs*lgv[2] + lbv[2];
    float t3 = (vals[3]-m)*rs*lgv[3] + lbv[3];
    xo.x = t0; xo.y = t1; xo.z = t2; xo.w = t3;
    xb4[0]=f2bf(t0); xb4[1]=f2bf(t1); xb4[2]=f2bf(t2); xb4[3]=f2bf(t3);
    *(float4*)&xlnf[base] = xo;
    *(short4_t*)&xlnb[base] = *(short4_t*)xb4;
}

// final BN + leaky + transpose TM -> d_out [n][c][t], raw sums
__global__ __launch_bounds__(256) void k_bn_out_t(const float* __restrict__ x,
    const float* __restrict__ acc, const float* __restrict__ g, const float* __restrict__ b,
    float* __restrict__ out)
{
    __shared__ float tile[64][65];
    int nt0 = blockIdx.x*64, c0 = blockIdx.y*64;
    int w = threadIdx.x >> 6, lane = threadIdx.x & 63;
    int n = nt0 >> 7, t0 = nt0 & 127;
    int c = c0 + lane;
    float2 f = bn_fin(acc[c], acc[CC + c]);
    float gg = f.y*g[c], mm = f.x, bb = b[c];
    #pragma unroll
    for (int it = 0; it < 16; it++) {
        int tok = it*4 + w;
        float v = x[(size_t)(nt0 + tok)*CC + c];
        v = (v - mm)*gg + bb;
        v = v > 0.f ? v : SLOPE*v;
        tile[tok][lane] = v;
    }
    __syncthreads();
    #pragma unroll
    for (int it = 0; it < 16; it++) {
        int c_l = it*4 + w;
        out[(size_t)(n*CC + c0 + c_l)*TT + t0 + lane] = tile[lane][c_l];
    }
}

// BatchNorm over n only (relay path), x/out [N,C]
__global__ __launch_bounds__(64) void k_bn_relay(const float* __restrict__ x,
    float* __restrict__ out, const float* __restrict__ g, const float* __restrict__ b, int leaky)
{
    int c = blockIdx.x, tid = threadIdx.x;
    float s = 0.f, ss = 0.f;
    for (int n = tid; n < NN; n += 64) { float v = x[(size_t)n*CC + c]; s += v; ss += v*v; }
    for (int off = 32; off; off >>= 1) { s += __shfl_down(s, off); ss += __shfl_down(ss, off); }
    float S = __shfl(s, 0), SS = __shfl(ss, 0);
    float m = S / NN;
    float var = SS / NN - m*m; if (var < 0.f) var = 0.f;
    float rs = rsqrtf(var + EPS_BN);
    float gg = g[c]*rs, bb = b[c];
    for (int n = tid; n < NN; n += 64) {
        float v = (x[(size_t)n*CC + c] - m)*gg + bb;
        if (leaky) v = v > 0.f ? v : SLOPE*v;
        out[(size_t)n*CC + c] = v;
    }
}

// ---------------------------------------------------------------------------
// relay cross-attention; ykv TM f32 [nt][512] (k|v); rel [n][1280]
// (tr_k at +512, tr_v at +768, tr_q at +1024)
__global__ __launch_bounds__(64) void k_attn_tr(
    const float* __restrict__ rel, const float* __restrict__ ykv,
    const float* __restrict__ relay, float* __restrict__ out)
{
    int h = blockIdx.x, n = blockIdx.y, tid = threadIdx.x;
    __shared__ float sc[LL1];
    __shared__ float red[64][33];
    float q0[32];
    const float* qp = rel + (size_t)n*1280 + 1024 + h*32;
    #pragma unroll
    for (int j = 0; j < 8; j++) {
        float4 v = *(const float4*)&qp[j*4];
        q0[j*4] = v.x; q0[j*4+1] = v.y; q0[j*4+2] = v.z; q0[j*4+3] = v.w;
    }
    for (int l = tid; l < LL1; l += 64) {
        const float* kp = (l == 0) ? (rel + (size_t)n*1280 + 512 + h*32)
                                   : (ykv + (size_t)(n*TT + l-1)*512 + h*32);
        float s = 0.f;
        #pragma unroll
        for (int j = 0; j < 8; j++) {
            float4 v = *(const float4*)&kp[j*4];
            s += q0[j*4]*v.x + q0[j*4+1]*v.y + q0[j*4+2]*v.z + q0[j*4+3]*v.w;
        }
        sc[l] = s * SCALE_F;
    }
    __syncthreads();
    float mx = -1e30f;
    for (int l = tid; l < LL1; l += 64) mx = fmaxf(mx, sc[l]);
    for (int off = 32; off; off >>= 1) mx = fmaxf(mx, __shfl_xor(mx, off));
    float sum = 0.f;
    for (int l = tid; l < LL1; l += 64) { float e = expf(sc[l]-mx); sc[l] = e; sum += e; }
    for (int off = 32; off; off >>= 1) sum += __shfl_xor(sum, off);
    __syncthreads();
    float av[32];
    #pragma unroll
    for (int d = 0; d < 32; d++) av[d] = 0.f;
    for (int l = tid; l < LL1; l += 64) {
        float e = sc[l];
        const float* vp = (l == 0) ? (rel + (size_t)n*1280 + 768 + h*32)
                                   : (ykv + (size_t)(n*TT + l-1)*512 + 256 + h*32);
        #pragma unroll
        for (int j = 0; j < 8; j++) {
            float4 v = *(const float4*)&vp[j*4];
            av[j*4] += e*v.x; av[j*4+1] += e*v.y; av[j*4+2] += e*v.z; av[j*4+3] += e*v.w;
        }
    }
    #pragma unroll
    for (int d = 0; d < 32; d++) red[tid][d] = av[d];
    __syncthreads();
    if (tid < 32) {
        float a = 0.f;
        for (int k = 0; k < 64; k++) a += red[k][tid];
        a /= sum;
        int idx = n*CC + h*32 + tid;
        out[idx] = relay[idx] + a;
    }
}

// ---------------------------------------------------------------------------
extern "C" void kernel_launch(void* const* d_in, const int* in_sizes, int n_in,
                              void* d_out, int out_size, void* d_ws, size_t ws_size,
                              hipStream_t stream)
{
    const float* data    = (const float*)d_in[0];
    const float* ln_g    = (const float*)d_in[1];
    const float* ln_b    = (const float*)d_in[2];
    const float* tj_wq   = (const float*)d_in[3];
    const float* tj_bq   = (const float*)d_in[4];
    const float* tj_wk   = (const float*)d_in[5];
    const float* tj_bk   = (const float*)d_in[6];
    const float* tj_wv   = (const float*)d_in[7];
    const float* tj_bv   = (const float*)d_in[8];
    const float* tj_bn_g = (const float*)d_in[9];
    const float* tj_bn_b = (const float*)d_in[10];
    const float* tj_w1   = (const float*)d_in[11];
    const float* tj_b1   = (const float*)d_in[12];
    const float* tj_w2   = (const float*)d_in[13];
    const float* tj_b2   = (const float*)d_in[14];
    const float* tj_fbn_g= (const float*)d_in[15];
    const float* tj_fbn_b= (const float*)d_in[16];
    const float* tr_wq   = (const float*)d_in[17];
    const float* tr_bq   = (const float*)d_in[18];
    const float* tr_wk   = (const float*)d_in[19];
    const float* tr_bk   = (const float*)d_in[20];
    const float* tr_wv   = (const float*)d_in[21];
    const float* tr_bv   = (const float*)d_in[22];
    const float* tr_bn_g = (const float*)d_in[23];
    const float* tr_bn_b = (const float*)d_in[24];
    const float* tr_w1   = (const float*)d_in[25];
    const float* tr_b1   = (const float*)d_in[26];
    const float* tr_w2   = (const float*)d_in[27];
    const float* tr_b2   = (const float*)d_in[28];
    const float* tr_fbn_g= (const float*)d_in[29];
    const float* tr_fbn_b= (const float*)d_in[30];

    const size_t SZ = (size_t)NT*CC;     // 6,553,600
    const size_t SZ_NC = (size_t)NN*CC;

    // ws ~175 MB (R2's 186 passed)
    float* ws = (float*)d_ws;
    size_t off = 0;
    auto alloc = [&](size_t nf) { float* p = ws + off; off += nf; return p; };
    float*    nodesf  = alloc(SZ);          // TM f32: xln (layer0 LN in-place)
    float*    sbuf    = alloc(SZ);          // TM f32: s1 / s1b (FFN2 in-place)
    float*    P1      = alloc(SZ*5/2);      // qkv(1.5)+ekv(1.0) bf16 | h(2.0) bf16 | ykv(2.0) f32
    ushort_t* xs_bf   = (ushort_t*)alloc(SZ/2);  // xln_bf / s2_bf (TM)
    ushort_t* embs_bf = (ushort_t*)alloc(SZ/2);  // TM, persists
    ushort_t* nb_bf   = (ushort_t*)alloc(SZ/2);  // nodes bf16 (pre-LN), for ykv
    float* accs   = alloc(8*512);           // raw BN sums, 2 per layer
    float* relayA = alloc(SZ_NC);
    float* relayB = alloc(SZ_NC);
    float* rel    = alloc((size_t)NN*1280); // fused relay projections
    float* ret0   = alloc(SZ_NC);
    float* rret   = alloc(SZ_NC);
    float* ro     = alloc(SZ_NC);
    float* rh     = alloc((size_t)NN*DFFF);
    ushort_t* wqkv_bf  = (ushort_t*)alloc((size_t)ITER*768*CC/2);
    ushort_t* wkvtr_bf = (ushort_t*)alloc((size_t)ITER*512*CC/2);
    ushort_t* w1_bf    = (ushort_t*)alloc((size_t)ITER*DFFF*CC/2);
    ushort_t* w2_bf    = (ushort_t*)alloc((size_t)ITER*DFFF*CC/2);
    float* wrel  = alloc((size_t)ITER*1280*CC);
    float* brel  = alloc((size_t)ITER*1280);
    float* bqkv  = alloc((size_t)ITER*768);
    float* bkvtr = alloc((size_t)ITER*512);
    (void)ws_size; (void)in_sizes; (void)n_in; (void)out_size;

    ushort_t* qkv_tm = (ushort_t*)P1;           // [nt][768] bf16
    ushort_t* ekv_tm = qkv_tm + 3*SZ;           // [nt][512] bf16
    ushort_t* h_us   = (ushort_t*)P1;           // [nt][1024] bf16 (after attn)
    float*    ykv_f  = P1;                      // [nt][512] f32 (after FFN2)

    const int TCC = ITER*CC*CC, TFF = ITER*DFFF*CC;
    k_zero<<<16, 256, 0, stream>>>(accs, 8*512);
    k_cast2<<<(TCC+255)/256, 256, 0, stream>>>(tj_wq, wqkv_bf,          65536, 196608, TCC);
    k_cast2<<<(TCC+255)/256, 256, 0, stream>>>(tj_wk, wqkv_bf +  65536, 65536, 196608, TCC);
    k_cast2<<<(TCC+255)/256, 256, 0, stream>>>(tj_wv, wqkv_bf + 131072, 65536, 196608, TCC);
    k_cast2<<<(TCC+255)/256, 256, 0, stream>>>(tr_wk, wkvtr_bf,         65536, 131072, TCC);
    k_cast2<<<(TCC+255)/256, 256, 0, stream>>>(tr_wv, wkvtr_bf + 65536, 65536, 131072, TCC);
    k_cast2<<<(TFF+255)/256, 256, 0, stream>>>(tj_w1, w1_bf, TFF, TFF, TFF);
    k_cast2<<<(TFF+255)/256, 256, 0, stream>>>(tj_w2, w2_bf, TFF, TFF, TFF);
    k_copy2<<<(ITER*256+255)/256, 256, 0, stream>>>(tj_bq, bqkv,       256, 768, ITER*256);
    k_copy2<<<(ITER*256+255)/256, 256, 0, stream>>>(tj_bk, bqkv + 256, 256, 768, ITER*256);
    k_copy2<<<(ITER*256+255)/256, 256, 0, stream>>>(tj_bv, bqkv + 512, 256, 768, ITER*256);
    k_copy2<<<(ITER*256+255)/256, 256, 0, stream>>>(tr_bk, bkvtr,      256, 512, ITER*256);
    k_copy2<<<(ITER*256+255)/256, 256, 0, stream>>>(tr_bv, bkvtr+256,  256, 512, ITER*256);
    // fused relay weight block [1280 x 256] per layer: tj_k|tj_v|tr_k|tr_v|tr_q
    k_copy2<<<(TCC+255)/256, 256, 0, stream>>>(tj_wk, wrel,          65536, 327680, TCC);
    k_copy2<<<(TCC+255)/256, 256, 0, stream>>>(tj_wv, wrel +  65536, 65536, 327680, TCC);
    k_copy2<<<(TCC+255)/256, 256, 0, stream>>>(tr_wk, wrel + 131072, 65536, 327680, TCC);
    k_copy2<<<(TCC+255)/256, 256, 0, stream>>>(tr_wv, wrel + 196608, 65536, 327680, TCC);
    k_copy2<<<(TCC+255)/256, 256, 0, stream>>>(tr_wq, wrel + 262144, 65536, 327680, TCC);
    k_copy2<<<(ITER*256+255)/256, 256, 0, stream>>>(tj_bk, brel,        256, 1280, ITER*256);
    k_copy2<<<(ITER*256+255)/256, 256, 0, stream>>>(tj_bv, brel +  256, 256, 1280, ITER*256);
    k_copy2<<<(ITER*256+255)/256, 256, 0, stream>>>(tr_bk, brel +  512, 256, 1280, ITER*256);
    k_copy2<<<(ITER*256+255)/256, 256, 0, stream>>>(tr_bv, brel +  768, 256, 1280, ITER*256);
    k_copy2<<<(ITER*256+255)/256, 256, 0, stream>>>(tr_bq, brel + 1024, 256, 1280, ITER*256);

    k_embed<<<dim3(8, NN), 128, 0, stream>>>(data, nodesf, embs_bf, relayA);
    // layer 0 LN (layers 1-3 get xln from fused k_bn_ln)
    k_layernorm<<<NT/4, 256, 0, stream>>>(nodesf, xs_bf, ln_g, ln_b);

    float* relay = relayA;
    float* relay_next = relayB;
    dim3 sb16(16, 16);

    for (int i = 0; i < ITER; i++) {
        const size_t woff = (size_t)i*DFFF*CC;
        float* accA = accs + i*1024;
        float* accB = accs + i*1024 + 512;

        // fused relay projections: rel[n][1280] (layer3 needs only first 512)
        k_sgemm<<<dim3((i == ITER-1) ? 32 : 80, 13), sb16, 0, stream>>>(
            wrel + (size_t)i*1280*CC, relay, brel + i*1280, nullptr, rel, CC, 1280, 0);

        // qkv: [nt][768] bf16
        k_gemm_mfma<<<200*6, 256, 0, stream>>>(
            xs_bf, wqkv_bf + (size_t)i*768*CC, bqkv + i*768, nullptr, nullptr, nullptr, nullptr,
            nullptr, qkv_tm, CC, 768, 6, FL_BF16);
        // ekv: [nt][512] bf16 (weight rows 256..767)
        k_gemm_mfma<<<200*4, 256, 0, stream>>>(
            embs_bf, wqkv_bf + (size_t)i*768*CC + 65536, bqkv + i*768 + 256,
            nullptr, nullptr, nullptr, nullptr,
            nullptr, ekv_tm, CC, 512, 4, FL_BF16);

        k_attn_tj<<<dim3(NHH, NN), 128, 0, stream>>>(qkv_tm, ekv_tm, rel, nodesf, sbuf);

        k_bnstats_tm<<<NN, 256, 0, stream>>>(sbuf, accA);
        k_bn_apply_raw<<<SZ/1024, 256, 0, stream>>>(
            sbuf, accA, tj_bn_g + i*CC, tj_bn_b + i*CC, xs_bf);

        // FFN1: h = relu(W1*s2+b1), [nt][1024] bf16
        k_gemm_mfma<<<200*8, 256, 0, stream>>>(
            xs_bf, w1_bf + woff, tj_b1 + i*DFFF, nullptr, nullptr, nullptr, nullptr,
            nullptr, h_us, CC, DFFF, 8, FL_RELU | FL_BF16);
        // FFN2: sbuf = W2*h + b2 + BN1(sbuf) (in-place, per-thread idx safe)
        k_gemm_mfma<<<200*2, 256, 0, stream>>>(
            h_us, w2_bf + woff, tj_b2 + i*CC, sbuf, accA, tj_bn_g + i*CC, tj_bn_b + i*CC,
            sbuf, nullptr, DFFF, CC, 2, FL_RESBN);

        k_bnstats_tm<<<NN, 256, 0, stream>>>(sbuf, accB);
        if (i == ITER-1) {
            k_bn_out_t<<<dim3(NT/64, CC/64), 256, 0, stream>>>(
                sbuf, accB, tj_fbn_g + i*CC, tj_fbn_b + i*CC, (float*)d_out);
            break;   // last relay update is dead code
        }
        // fused BN2+leaky+LN(i+1): nodes_bf + xln f32 + xln bf16
        k_bn_ln<<<NT/4, 256, 0, stream>>>(
            sbuf, accB, tj_fbn_g + i*CC, tj_fbn_b + i*CC,
            ln_g + (i+1)*CC, ln_b + (i+1)*CC, nodesf, xs_bf, nb_bf);

        // relay path: ykv = W_kv^tr * nodes, [nt][512] f32
        k_gemm_mfma<<<200*4, 256, 0, stream>>>(
            nb_bf, wkvtr_bf + (size_t)i*512*CC, bkvtr + i*512,
            nullptr, nullptr, nullptr, nullptr,
            ykv_f, nullptr, CC, 512, 4, 0);

        k_attn_tr<<<dim3(NHH, NN), 64, 0, stream>>>(rel, ykv_f, relay, ret0);
        k_bn_relay<<<CC, 64, 0, stream>>>(ret0, rret, tr_bn_g + i*CC, tr_bn_b + i*CC, 0);

        k_sgemm<<<dim3(DFFF/16, (NN+15)/16), sb16, 0, stream>>>(
            tr_w1 + woff, rret, tr_b1 + i*DFFF, nullptr, rh, CC, DFFF, 1);
        k_sgemm<<<dim3(16, (NN+15)/16), sb16, 0, stream>>>(
            tr_w2 + woff, rh, tr_b2 + i*CC, rret, ro, DFFF, CC, 0);
        k_bn_relay<<<CC, 64, 0, stream>>>(ro, relay_next, tr_fbn_g + i*CC, tr_fbn_b + i*CC, 1);

        float* tmp = relay; relay = relay_next; relay_next = tmp;
    }
}